// Round 4
// baseline (52796.246 us; speedup 1.0000x reference)
//
#include <hip/hip_runtime.h>
#include <hip/hip_bf16.h>

using bf16   = __bf16;
using bf16x8 = __attribute__((ext_vector_type(8))) __bf16;
using f32x4  = __attribute__((ext_vector_type(4))) float;

#define TSTEPS 255
// element (bf16) counts
#define UNITE  512              // elements per 1KiB MFMA fragment unit
#define HPAR   (16*16*512)      // one (parity,part) h buffer: 16 tm x 16 kb units
#define WA_UNITS_DIR (128*24)
#define WB_UNITS_DIR (128*32)
#define WC_UNITS_DIR (16*16)

#define MFMA(acc, a, b) acc = __builtin_amdgcn_mfma_f32_16x16x32_bf16((a), (b), (acc), 0, 0, 0)

__device__ __forceinline__ float sigmoidf_(float x) { return 1.f / (1.f + __expf(-x)); }
__device__ __forceinline__ float tanhf_(float x) {
    float e = __expf(-2.f * fabsf(x));
    float t = (1.f - e) / (1.f + e);
    return copysignf(t, x);
}

// fp32x8 -> (bf16 hi, bf16 lo) x8.  lo = rnd(v - hi).
__device__ __forceinline__ void split_store8(const float* __restrict__ src,
                                             bf16* __restrict__ dh, bf16* __restrict__ dl) {
    float f[8];
    *(float4*)f       = *(const float4*)src;
    *(float4*)(f + 4) = *(const float4*)(src + 4);
    bf16x8 oh, ol;
    #pragma unroll
    for (int j = 0; j < 8; ++j) { bf16 h = (bf16)f[j]; oh[j] = h; ol[j] = (bf16)(f[j] - (float)h); }
    *(bf16x8*)dh = oh; *(bf16x8*)dl = ol;
}

// ---------------- software grid barrier (256 blocks co-resident) ----------------
// Single arrival counter, ONE poller per block (thread 0) with s_sleep between
// polls -> poll traffic ~1 line/block instead of 64 KB/grid-sweep (R3's poll storm
// moved ~28 GB and throttled the fabric to 330 GB/s).
// Monotonic target 256*epoch (epoch 1..512) -> no reset race, no overflow.
// Memory ordering: per-thread __threadfence() before arrival (release: h stores
// visible agent-wide, ordered before the add by fence+syncthreads) and after the
// wait (acquire: invalidate stale L1/L2 before reading other blocks' h).
__device__ __forceinline__ void gbarrier(unsigned* __restrict__ cnt, unsigned epoch) {
    __threadfence();
    __syncthreads();
    if (threadIdx.x == 0) {
        __hip_atomic_fetch_add(cnt, 1u, __ATOMIC_RELAXED, __HIP_MEMORY_SCOPE_AGENT);
        while (__hip_atomic_load(cnt, __ATOMIC_RELAXED, __HIP_MEMORY_SCOPE_AGENT) < 256u * epoch)
            __builtin_amdgcn_s_sleep(8);
    }
    __syncthreads();
    __threadfence();
}

// ---------------- precompute kernels ----------------

// WA[dir][n][k]: k<256 -> wih0[n][k], else whh0[n][k-256]; packed B-fragments, hi/lo.
__global__ void k_pack_wa(const float* __restrict__ wihL, const float* __restrict__ whhL,
                          const float* __restrict__ wihR, const float* __restrict__ whhR,
                          bf16* __restrict__ wah, bf16* __restrict__ wal) {
    int gid = blockIdx.x * 256 + threadIdx.x;      // 393,216
    int lane = gid & 63, u = gid >> 6;             // u < 6144
    int kb = u % 24; int tn = (u / 24) & 127; int dir = u / 3072;
    int r = lane & 15, q = lane >> 4;
    int n = tn * 16 + r, k = kb * 32 + q * 8;
    const float* wih = dir ? wihR : wihL;          // layer 0 slice at offset 0
    const float* whh = dir ? whhR : whhL;
    const float* src = (k < 256) ? (wih + (size_t)n * 256 + k)
                                 : (whh + (size_t)n * 512 + (k - 256));
    split_store8(src, wah + (size_t)u * UNITE + lane * 8, wal + (size_t)u * UNITE + lane * 8);
}

// Wcomb[dir][n][k] = sum_v wih1[n][v] * wfc0[v][k]   (fp32 scratch)
__global__ void k_wcomb(const float* __restrict__ wihL, const float* __restrict__ wfcL,
                        const float* __restrict__ wihR, const float* __restrict__ wfcR,
                        float* __restrict__ wcf) {
    size_t gid = (size_t)blockIdx.x * 256 + threadIdx.x;  // 2,097,152
    int k = gid & 511; int n = (gid >> 9) & 2047; int dir = (int)(gid >> 20);
    const float* wih1 = (dir ? wihR : wihL) + (size_t)2048 * 256;  // layer 1
    const float* wfc0 = (dir ? wfcR : wfcL);                        // layer 0
    float s = 0.f;
    #pragma unroll 8
    for (int v = 0; v < 256; ++v)
        s = fmaf(wih1[(size_t)n * 256 + v], wfc0[(size_t)v * 512 + k], s);
    wcf[gid] = s;
}

// WB[dir][n][k]: k<512 -> Wcomb[n][k], else whh1[n][k-512]; packed B-fragments, hi/lo.
__global__ void k_pack_wb(const float* __restrict__ whhL, const float* __restrict__ whhR,
                          const float* __restrict__ wcf,
                          bf16* __restrict__ wbh, bf16* __restrict__ wbl) {
    int gid = blockIdx.x * 256 + threadIdx.x;      // 524,288
    int lane = gid & 63, u = gid >> 6;             // u < 8192
    int kb = u & 31, tn = (u >> 5) & 127, dir = u >> 12;
    int r = lane & 15, q = lane >> 4;
    int n = tn * 16 + r, k = kb * 32 + q * 8;
    const float* src;
    if (k < 512) {
        src = wcf + ((size_t)dir * 2048 + n) * 512 + k;
    } else {
        const float* whh1 = (dir ? whhR : whhL) + (size_t)2048 * 512;
        src = whh1 + (size_t)n * 512 + (k - 512);
    }
    split_store8(src, wbh + (size_t)u * UNITE + lane * 8, wbl + (size_t)u * UNITE + lane * 8);
}

// WC[dir][n=vout][k=h] = wfc1[vout][h]; packed B-fragments, hi/lo.
__global__ void k_pack_wc(const float* __restrict__ wfcL, const float* __restrict__ wfcR,
                          bf16* __restrict__ wch, bf16* __restrict__ wcl) {
    int gid = blockIdx.x * 256 + threadIdx.x;      // 32,768
    int lane = gid & 63, u = gid >> 6;             // u < 512
    int kb = u & 15, tn = (u >> 4) & 15, dir = u >> 8;
    int r = lane & 15, q = lane >> 4;
    int n = tn * 16 + r, k = kb * 32 + q * 8;
    const float* wfc1 = (dir ? wfcR : wfcL) + (size_t)256 * 512;   // layer 1
    split_store8(wfc1 + (size_t)n * 512 + k,
                 wch + (size_t)u * UNITE + lane * 8, wcl + (size_t)u * UNITE + lane * 8);
}

// bA = bih0+bhh0 ; bB = bih1+bhh1 + bfc0 @ wih1^T ; bC = bfc1   (all fp32, exact)
__global__ void k_bias(const float* __restrict__ bihL, const float* __restrict__ bhhL,
                       const float* __restrict__ bfcL, const float* __restrict__ wihL,
                       const float* __restrict__ bihR, const float* __restrict__ bhhR,
                       const float* __restrict__ bfcR, const float* __restrict__ wihR,
                       float* __restrict__ ba, float* __restrict__ bb, float* __restrict__ bc) {
    int gid = blockIdx.x * 256 + threadIdx.x;      // 4096
    int n = gid & 2047, dir = gid >> 11;
    const float* bih = dir ? bihR : bihL;
    const float* bhh = dir ? bhhR : bhhL;
    const float* bfc = dir ? bfcR : bfcL;
    const float* wih1 = (dir ? wihR : wihL) + (size_t)2048 * 256;
    ba[dir * 2048 + n] = bih[n] + bhh[n];
    float s = bih[2048 + n] + bhh[2048 + n];
    #pragma unroll 8
    for (int v = 0; v < 256; ++v)
        s = fmaf(bfc[v], wih1[(size_t)n * 256 + v], s);
    bb[dir * 2048 + n] = s;
    if (n < 256) bc[dir * 256 + n] = bfc[256 + n];
}

// ---------------- main persistent kernel (plain launch + software barrier) ----------------
// 256 blocks x 256 threads (1 block/CU -> co-resident). bid: dir = bid&1, sb = bid>>1:
//   mq = sb&3  -> batch quadrant, wave wv owns 16-row tile tm = mq*4+wv
//   nslc = sb>>2 (0..31) -> hidden cols [nslc*16, +16) for BOTH layers
// All GEMM products use 2-term bf16 splits on both operands (3 MFMAs per product)
// -> ~fp32-accurate; c-state fp32 in VGPRs; h stored as bf16 hi/lo pair in packed
// MFMA A-fragment layout.
__global__ __launch_bounds__(256) void bilstm_main(
    const float* __restrict__ x,
    const bf16* __restrict__ wah, const bf16* __restrict__ wal,
    const bf16* __restrict__ wbh, const bf16* __restrict__ wbl,
    const bf16* __restrict__ wch, const bf16* __restrict__ wcl,
    bf16* __restrict__ h0pk, bf16* __restrict__ h1pk,
    const float* __restrict__ ba, const float* __restrict__ bb,
    const float* __restrict__ bc, float* __restrict__ out,
    unsigned* __restrict__ cnt)
{
    const int bid  = blockIdx.x;
    const int dir  = bid & 1;
    const int sb   = bid >> 1;
    const int mq   = sb & 3;
    const int nslc = sb >> 2;
    const int wv   = threadIdx.x >> 6;
    const int lane = threadIdx.x & 63;
    const int r = lane & 15, q = lane >> 4;
    const int tm = mq * 4 + wv;

    const bf16* WAh = wah + (size_t)dir * WA_UNITS_DIR * UNITE;
    const bf16* WAl = wal + (size_t)dir * WA_UNITS_DIR * UNITE;
    const bf16* WBh = wbh + (size_t)dir * WB_UNITS_DIR * UNITE;
    const bf16* WBl = wbl + (size_t)dir * WB_UNITS_DIR * UNITE;
    const bf16* WCh = wch + (size_t)dir * WC_UNITS_DIR * UNITE;
    const bf16* WCl = wcl + (size_t)dir * WC_UNITS_DIR * UNITE;
    bf16* H0 = h0pk + (size_t)dir * 4 * HPAR;   // [parity][part][HPAR]
    bf16* H1 = h1pk + (size_t)dir * 4 * HPAR;
    const float* BA = ba + dir * 2048;
    const float* BB = bb + dir * 2048;
    const float* BC = bc + dir * 256;

    const int col = nslc * 16 + r;               // hidden col this lane owns
    const int blkK = col >> 5;
    const int kl = col & 31;
    // packed A-layout address of element (row m, hidden col `col`):
    // unit (tm*16+blkK), elem (kl>>3)*128 + m*8 + (kl&7); this thread's rows m=4q+i.
    const size_t hw_base = (size_t)(tm * 16 + blkK) * UNITE
                         + (size_t)(kl >> 3) * 128 + (size_t)(4 * q) * 8 + (kl & 7);

    const float bia0 = BA[col], bia1 = BA[512 + col], bia2 = BA[1024 + col], bia3 = BA[1536 + col];
    const float bib0 = BB[col], bib1 = BB[512 + col], bib2 = BB[1024 + col], bib3 = BB[1536 + col];

    // y-tile assignment: per dir 512 wave-slots = 16 tm x 16 tn x 2 k-halves
    const int yid = sb * 4 + wv;
    const int ytm = yid & 15, ytn = (yid >> 4) & 15, ykh = yid >> 8;
    const float byc = (ykh == 0) ? BC[ytn * 16 + r] : 0.f;

    f32x4 c0 = {0.f, 0.f, 0.f, 0.f}, c1 = {0.f, 0.f, 0.f, 0.f};
    unsigned epoch = 0;

    for (int t = 0; t <= TSTEPS; ++t) {
        const int pw = t & 1, pr = pw ^ 1;
        // -------- phase A: gates0 + elementwise (t<255) --------
        if (t < TSTEPS) {
            const int pos = dir ? (255 - t) : t;
            f32x4 acc[4] = {{0,0,0,0},{0,0,0,0},{0,0,0,0},{0,0,0,0}};
            const float* xp = x + ((size_t)(tm * 16 + r) * 256 + pos) * 256 + q * 8;
            const bf16* ahh_p = H0 + (size_t)pr * 2 * HPAR + (size_t)(tm * 16) * UNITE + lane * 8;
            const bf16* ahl_p = ahh_p + HPAR;
            #pragma unroll
            for (int kb = 0; kb < 8; ++kb) {        // x part (K 0..255), split in-register
                float xf[8];
                *(float4*)xf       = *(const float4*)(xp + kb * 32);
                *(float4*)(xf + 4) = *(const float4*)(xp + kb * 32 + 4);
                bf16x8 axh, axl;
                #pragma unroll
                for (int j = 0; j < 8; ++j) { bf16 h = (bf16)xf[j]; axh[j] = h; axl[j] = (bf16)(xf[j] - (float)h); }
                #pragma unroll
                for (int g = 0; g < 4; ++g) {
                    const size_t wu = ((size_t)((g * 32 + nslc) * 24) + kb) * UNITE + lane * 8;
                    bf16x8 bh = *(const bf16x8*)(WAh + wu);
                    bf16x8 bl = *(const bf16x8*)(WAl + wu);
                    MFMA(acc[g], axh, bh); MFMA(acc[g], axh, bl); MFMA(acc[g], axl, bh);
                }
            }
            #pragma unroll
            for (int kb = 0; kb < 16; ++kb) {       // h0 part (K 256..767)
                bf16x8 ahh = *(const bf16x8*)(ahh_p + (size_t)kb * UNITE);
                bf16x8 ahl = *(const bf16x8*)(ahl_p + (size_t)kb * UNITE);
                #pragma unroll
                for (int g = 0; g < 4; ++g) {
                    const size_t wu = ((size_t)((g * 32 + nslc) * 24) + 8 + kb) * UNITE + lane * 8;
                    bf16x8 bh = *(const bf16x8*)(WAh + wu);
                    bf16x8 bl = *(const bf16x8*)(WAl + wu);
                    MFMA(acc[g], ahh, bh); MFMA(acc[g], ahh, bl); MFMA(acc[g], ahl, bh);
                }
            }
            bf16* HwH = H0 + (size_t)pw * 2 * HPAR;
            bf16* HwL = HwH + HPAR;
            #pragma unroll
            for (int i = 0; i < 4; ++i) {
                float gi = sigmoidf_(acc[0][i] + bia0);
                float gf = sigmoidf_(acc[1][i] + bia1);
                float gg = tanhf_   (acc[2][i] + bia2);
                float go = sigmoidf_(acc[3][i] + bia3);
                float cc = gf * c0[i] + gi * gg;
                c0[i] = cc;
                float hv = go * tanhf_(cc);
                bf16 hh = (bf16)hv;
                HwH[hw_base + (size_t)i * 8] = hh;
                HwL[hw_base + (size_t)i * 8] = (bf16)(hv - (float)hh);
            }
        }
        // -------- phase A: y(t-1) = h1(t-1) @ wfc1^T + bfc1 (t>=1) --------
        if (t >= 1) {
            const int py = (t - 1) & 1;
            f32x4 acc = {0, 0, 0, 0};
            const bf16* ayh = H1 + (size_t)py * 2 * HPAR + (size_t)(ytm * 16) * UNITE + lane * 8;
            const bf16* ayl = ayh + HPAR;
            const bf16* byh = WCh + (size_t)(ytn * 16) * UNITE + lane * 8;
            const bf16* byl = WCl + (size_t)(ytn * 16) * UNITE + lane * 8;
            #pragma unroll
            for (int kk = 0; kk < 8; ++kk) {
                int kb = ykh * 8 + kk;
                bf16x8 ah = *(const bf16x8*)(ayh + (size_t)kb * UNITE);
                bf16x8 al = *(const bf16x8*)(ayl + (size_t)kb * UNITE);
                bf16x8 bh = *(const bf16x8*)(byh + (size_t)kb * UNITE);
                bf16x8 bl = *(const bf16x8*)(byl + (size_t)kb * UNITE);
                MFMA(acc, ah, bh); MFMA(acc, ah, bl); MFMA(acc, al, bh);
            }
            const int tout = dir ? (255 + (t - 1)) : (t - 1);
            #pragma unroll
            for (int i = 0; i < 4; ++i) {
                size_t oidx = ((size_t)(ytm * 16 + 4 * q + i) * 510 + tout) * 256 + (ytn * 16 + r);
                atomicAdd(out + oidx, acc[i] + byc);
            }
        }
        ++epoch; gbarrier(cnt, epoch);
        // -------- phase B: gates1 + elementwise (t<255) --------
        if (t < TSTEPS) {
            f32x4 acc[4] = {{0,0,0,0},{0,0,0,0},{0,0,0,0},{0,0,0,0}};
            const bf16* a0h = H0 + (size_t)pw * 2 * HPAR + (size_t)(tm * 16) * UNITE + lane * 8;
            const bf16* a0l = a0h + HPAR;
            const bf16* a1h = H1 + (size_t)pr * 2 * HPAR + (size_t)(tm * 16) * UNITE + lane * 8;
            const bf16* a1l = a1h + HPAR;
            #pragma unroll
            for (int kb = 0; kb < 16; ++kb) {       // h0(t) part (K 0..511)
                bf16x8 ah = *(const bf16x8*)(a0h + (size_t)kb * UNITE);
                bf16x8 al = *(const bf16x8*)(a0l + (size_t)kb * UNITE);
                #pragma unroll
                for (int g = 0; g < 4; ++g) {
                    const size_t wu = ((size_t)((g * 32 + nslc) * 32) + kb) * UNITE + lane * 8;
                    bf16x8 bh = *(const bf16x8*)(WBh + wu);
                    bf16x8 bl = *(const bf16x8*)(WBl + wu);
                    MFMA(acc[g], ah, bh); MFMA(acc[g], ah, bl); MFMA(acc[g], al, bh);
                }
            }
            #pragma unroll
            for (int kb = 0; kb < 16; ++kb) {       // h1(t-1) part (K 512..1023)
                bf16x8 ah = *(const bf16x8*)(a1h + (size_t)kb * UNITE);
                bf16x8 al = *(const bf16x8*)(a1l + (size_t)kb * UNITE);
                #pragma unroll
                for (int g = 0; g < 4; ++g) {
                    const size_t wu = ((size_t)((g * 32 + nslc) * 32) + 16 + kb) * UNITE + lane * 8;
                    bf16x8 bh = *(const bf16x8*)(WBh + wu);
                    bf16x8 bl = *(const bf16x8*)(WBl + wu);
                    MFMA(acc[g], ah, bh); MFMA(acc[g], ah, bl); MFMA(acc[g], al, bh);
                }
            }
            bf16* HwH = H1 + (size_t)pw * 2 * HPAR;
            bf16* HwL = HwH + HPAR;
            #pragma unroll
            for (int i = 0; i < 4; ++i) {
                float gi = sigmoidf_(acc[0][i] + bib0);
                float gf = sigmoidf_(acc[1][i] + bib1);
                float gg = tanhf_   (acc[2][i] + bib2);
                float go = sigmoidf_(acc[3][i] + bib3);
                float cc = gf * c1[i] + gi * gg;
                c1[i] = cc;
                float hv = go * tanhf_(cc);
                bf16 hh = (bf16)hv;
                HwH[hw_base + (size_t)i * 8] = hh;
                HwL[hw_base + (size_t)i * 8] = (bf16)(hv - (float)hh);
            }
        }
        ++epoch; gbarrier(cnt, epoch);
    }
}

// ---------------- host launch ----------------
extern "C" void kernel_launch(void* const* d_in, const int* in_sizes, int n_in,
                              void* d_out, int out_size, void* d_ws, size_t ws_size,
                              hipStream_t stream) {
    (void)in_sizes; (void)n_in; (void)ws_size;
    const float* x    = (const float*)d_in[0];
    const float* wihL = (const float*)d_in[1];
    const float* whhL = (const float*)d_in[2];
    const float* bihL = (const float*)d_in[3];
    const float* bhhL = (const float*)d_in[4];
    const float* wfcL = (const float*)d_in[5];
    const float* bfcL = (const float*)d_in[6];
    const float* wihR = (const float*)d_in[7];
    const float* whhR = (const float*)d_in[8];
    const float* bihR = (const float*)d_in[9];
    const float* bhhR = (const float*)d_in[10];
    const float* wfcR = (const float*)d_in[11];
    const float* bfcR = (const float*)d_in[12];

    char* ws = (char*)d_ws;
    size_t off = 0;
    auto take = [&](size_t bytes) -> char* {
        off = (off + 255) & ~(size_t)255;
        char* p = ws + off;
        off += bytes;
        return p;
    };
    bf16*     WAH = (bf16*)take((size_t)2 * WA_UNITS_DIR * 1024);  // 6 MiB
    bf16*     WAL = (bf16*)take((size_t)2 * WA_UNITS_DIR * 1024);  // 6 MiB
    bf16*     WBH = (bf16*)take((size_t)2 * WB_UNITS_DIR * 1024);  // 8 MiB
    bf16*     WBL = (bf16*)take((size_t)2 * WB_UNITS_DIR * 1024);  // 8 MiB
    bf16*     WCH = (bf16*)take((size_t)2 * WC_UNITS_DIR * 1024);  // 0.5 MiB
    bf16*     WCL = (bf16*)take((size_t)2 * WC_UNITS_DIR * 1024);  // 0.5 MiB
    bf16*     H0  = (bf16*)take((size_t)8 * HPAR * 2);             // 2 MiB (dir x parity x part)
    bf16*     H1  = (bf16*)take((size_t)8 * HPAR * 2);             // 2 MiB
    float*    WCF = (float*)take((size_t)2 * 2048 * 512 * 4);      // 8 MiB fp32 scratch
    float*    BA  = (float*)take((size_t)2 * 2048 * 4);
    float*    BB  = (float*)take((size_t)2 * 2048 * 4);
    float*    BC  = (float*)take((size_t)2 * 256 * 4);
    unsigned* CNT = (unsigned*)take((size_t)256 * 4);              // barrier counter

    hipMemsetAsync(H0, 0, (size_t)8 * HPAR * 2, stream);
    hipMemsetAsync(H1, 0, (size_t)8 * HPAR * 2, stream);
    hipMemsetAsync(CNT, 0, (size_t)256 * 4, stream);               // clear 0xAA poison!
    hipMemsetAsync(d_out, 0, (size_t)out_size * 4, stream);

    k_pack_wa<<<1536, 256, 0, stream>>>(wihL, whhL, wihR, whhR, WAH, WAL);
    k_wcomb  <<<8192, 256, 0, stream>>>(wihL, wfcL, wihR, wfcR, WCF);
    k_pack_wb<<<2048, 256, 0, stream>>>(whhL, whhR, WCF, WBH, WBL);
    k_pack_wc<<<128,  256, 0, stream>>>(wfcL, wfcR, WCH, WCL);
    k_bias   <<<16,   256, 0, stream>>>(bihL, bhhL, bfcL, wihL, bihR, bhhR, bfcR, wihR, BA, BB, BC);

    bilstm_main<<<256, 256, 0, stream>>>(x, WAH, WAL, WBH, WBL, WCH, WCL,
                                         H0, H1, BA, BB, BC, (float*)d_out, CNT);
}

// Round 5
// 35038.837 us; speedup vs baseline: 1.5068x; 1.5068x over previous
//
#include <hip/hip_runtime.h>
#include <hip/hip_bf16.h>

using bf16   = __bf16;
using bf16x8 = __attribute__((ext_vector_type(8))) __bf16;
using f32x4  = __attribute__((ext_vector_type(4))) float;
using u32x4  = __attribute__((ext_vector_type(4))) unsigned int;

#define TSTEPS 255
// element (bf16) counts
#define UNITE  512              // elements per 1KiB MFMA fragment unit
#define HPAR   (16*16*512)      // one (parity,part) h buffer: 16 tm x 16 kb units
#define WA_UNITS_DIR (128*24)
#define WB_UNITS_DIR (128*32)
#define WC_UNITS_DIR (16*16)

#define MFMA(acc, a, b) acc = __builtin_amdgcn_mfma_f32_16x16x32_bf16((a), (b), (acc), 0, 0, 0)

__device__ __forceinline__ float sigmoidf_(float x) { return 1.f / (1.f + __expf(-x)); }
__device__ __forceinline__ float tanhf_(float x) {
    float e = __expf(-2.f * fabsf(x));
    float t = (1.f - e) / (1.f + e);
    return copysignf(t, x);
}

// Coherent (L1+L2-bypassing) 8x16B load: 4 units from each of two bases at
// stride 1KiB, single trailing waitcnt. sc0 sc1 -> read the device coherent
// point (IC), so cross-XCD h communication needs NO buffer_inv — which keeps
// the 29 MB weight set L2-resident (R4's 28.4 GB FETCH was the per-phase
// weight refetch caused by __threadfence()'s buffer_inv).
__device__ __forceinline__ void load8_coh(const bf16* ph, const bf16* pl,
                                          u32x4* h, u32x4* l) {
    asm volatile(
        "global_load_dwordx4 %0, %8, off sc0 sc1\n\t"
        "global_load_dwordx4 %1, %8, off offset:1024 sc0 sc1\n\t"
        "global_load_dwordx4 %2, %8, off offset:2048 sc0 sc1\n\t"
        "global_load_dwordx4 %3, %8, off offset:3072 sc0 sc1\n\t"
        "global_load_dwordx4 %4, %9, off sc0 sc1\n\t"
        "global_load_dwordx4 %5, %9, off offset:1024 sc0 sc1\n\t"
        "global_load_dwordx4 %6, %9, off offset:2048 sc0 sc1\n\t"
        "global_load_dwordx4 %7, %9, off offset:3072 sc0 sc1\n\t"
        "s_waitcnt vmcnt(0)"
        : "=&v"(h[0]), "=&v"(h[1]), "=&v"(h[2]), "=&v"(h[3]),
          "=&v"(l[0]), "=&v"(l[1]), "=&v"(l[2]), "=&v"(l[3])
        : "v"(ph), "v"(pl)
        : "memory");
}

// fp32x8 -> (bf16 hi, bf16 lo) x8.  lo = rnd(v - hi).
__device__ __forceinline__ void split_store8(const float* __restrict__ src,
                                             bf16* __restrict__ dh, bf16* __restrict__ dl) {
    float f[8];
    *(float4*)f       = *(const float4*)src;
    *(float4*)(f + 4) = *(const float4*)(src + 4);
    bf16x8 oh, ol;
    #pragma unroll
    for (int j = 0; j < 8; ++j) { bf16 h = (bf16)f[j]; oh[j] = h; ol[j] = (bf16)(f[j] - (float)h); }
    *(bf16x8*)dh = oh; *(bf16x8*)dl = ol;
}

// ---------------- software grid barrier, no cache invalidation ----------------
// Arrival: one RELEASE store per block (waitcnt + buffer_wbl2 + coherent store —
// writes back this XCD's dirty h lines; does NOT invalidate clean weight lines).
// __syncthreads() first: compiler drains each wave's vmem before s_barrier, so
// all 4 waves' h stores are in L2 before the wbl2. Wait: wave 0 sweeps all 256
// flags with relaxed agent-scope loads (coherent reads, no contended RMW).
// Epochs increase monotonically (1..512) -> no reset race.
__device__ __forceinline__ void gbarrier(unsigned* __restrict__ flags, int bid, unsigned epoch) {
    __syncthreads();
    if (threadIdx.x == 0)
        __hip_atomic_store(&flags[bid], epoch, __ATOMIC_RELEASE, __HIP_MEMORY_SCOPE_AGENT);
    if (threadIdx.x < 64) {
        const int l = threadIdx.x;
        for (;;) {
            unsigned f0 = __hip_atomic_load(&flags[l],       __ATOMIC_RELAXED, __HIP_MEMORY_SCOPE_AGENT);
            unsigned f1 = __hip_atomic_load(&flags[l + 64],  __ATOMIC_RELAXED, __HIP_MEMORY_SCOPE_AGENT);
            unsigned f2 = __hip_atomic_load(&flags[l + 128], __ATOMIC_RELAXED, __HIP_MEMORY_SCOPE_AGENT);
            unsigned f3 = __hip_atomic_load(&flags[l + 192], __ATOMIC_RELAXED, __HIP_MEMORY_SCOPE_AGENT);
            if (__all(f0 >= epoch && f1 >= epoch && f2 >= epoch && f3 >= epoch)) break;
            __builtin_amdgcn_s_sleep(1);
        }
    }
    __syncthreads();
}

// ---------------- precompute kernels ----------------

// WA[dir][n][k]: k<256 -> wih0[n][k], else whh0[n][k-256]; packed B-fragments, hi/lo.
__global__ void k_pack_wa(const float* __restrict__ wihL, const float* __restrict__ whhL,
                          const float* __restrict__ wihR, const float* __restrict__ whhR,
                          bf16* __restrict__ wah, bf16* __restrict__ wal) {
    int gid = blockIdx.x * 256 + threadIdx.x;      // 393,216
    int lane = gid & 63, u = gid >> 6;             // u < 6144
    int kb = u % 24; int tn = (u / 24) & 127; int dir = u / 3072;
    int r = lane & 15, q = lane >> 4;
    int n = tn * 16 + r, k = kb * 32 + q * 8;
    const float* wih = dir ? wihR : wihL;          // layer 0 slice at offset 0
    const float* whh = dir ? whhR : whhL;
    const float* src = (k < 256) ? (wih + (size_t)n * 256 + k)
                                 : (whh + (size_t)n * 512 + (k - 256));
    split_store8(src, wah + (size_t)u * UNITE + lane * 8, wal + (size_t)u * UNITE + lane * 8);
}

// Wcomb[dir][n][k] = sum_v wih1[n][v] * wfc0[v][k]   (fp32 scratch)
__global__ void k_wcomb(const float* __restrict__ wihL, const float* __restrict__ wfcL,
                        const float* __restrict__ wihR, const float* __restrict__ wfcR,
                        float* __restrict__ wcf) {
    size_t gid = (size_t)blockIdx.x * 256 + threadIdx.x;  // 2,097,152
    int k = gid & 511; int n = (gid >> 9) & 2047; int dir = (int)(gid >> 20);
    const float* wih1 = (dir ? wihR : wihL) + (size_t)2048 * 256;  // layer 1
    const float* wfc0 = (dir ? wfcR : wfcL);                        // layer 0
    float s = 0.f;
    #pragma unroll 8
    for (int v = 0; v < 256; ++v)
        s = fmaf(wih1[(size_t)n * 256 + v], wfc0[(size_t)v * 512 + k], s);
    wcf[gid] = s;
}

// WB[dir][n][k]: k<512 -> Wcomb[n][k], else whh1[n][k-512]; packed B-fragments, hi/lo.
__global__ void k_pack_wb(const float* __restrict__ whhL, const float* __restrict__ whhR,
                          const float* __restrict__ wcf,
                          bf16* __restrict__ wbh, bf16* __restrict__ wbl) {
    int gid = blockIdx.x * 256 + threadIdx.x;      // 524,288
    int lane = gid & 63, u = gid >> 6;             // u < 8192
    int kb = u & 31, tn = (u >> 5) & 127, dir = u >> 12;
    int r = lane & 15, q = lane >> 4;
    int n = tn * 16 + r, k = kb * 32 + q * 8;
    const float* src;
    if (k < 512) {
        src = wcf + ((size_t)dir * 2048 + n) * 512 + k;
    } else {
        const float* whh1 = (dir ? whhR : whhL) + (size_t)2048 * 512;
        src = whh1 + (size_t)n * 512 + (k - 512);
    }
    split_store8(src, wbh + (size_t)u * UNITE + lane * 8, wbl + (size_t)u * UNITE + lane * 8);
}

// WC[dir][n=vout][k=h] = wfc1[vout][h]; packed B-fragments, hi/lo.
__global__ void k_pack_wc(const float* __restrict__ wfcL, const float* __restrict__ wfcR,
                          bf16* __restrict__ wch, bf16* __restrict__ wcl) {
    int gid = blockIdx.x * 256 + threadIdx.x;      // 32,768
    int lane = gid & 63, u = gid >> 6;             // u < 512
    int kb = u & 15, tn = (u >> 4) & 15, dir = u >> 8;
    int r = lane & 15, q = lane >> 4;
    int n = tn * 16 + r, k = kb * 32 + q * 8;
    const float* wfc1 = (dir ? wfcR : wfcL) + (size_t)256 * 512;   // layer 1
    split_store8(wfc1 + (size_t)n * 512 + k,
                 wch + (size_t)u * UNITE + lane * 8, wcl + (size_t)u * UNITE + lane * 8);
}

// bA = bih0+bhh0 ; bB = bih1+bhh1 + bfc0 @ wih1^T ; bC = bfc1   (all fp32, exact)
__global__ void k_bias(const float* __restrict__ bihL, const float* __restrict__ bhhL,
                       const float* __restrict__ bfcL, const float* __restrict__ wihL,
                       const float* __restrict__ bihR, const float* __restrict__ bhhR,
                       const float* __restrict__ bfcR, const float* __restrict__ wihR,
                       float* __restrict__ ba, float* __restrict__ bb, float* __restrict__ bc) {
    int gid = blockIdx.x * 256 + threadIdx.x;      // 4096
    int n = gid & 2047, dir = gid >> 11;
    const float* bih = dir ? bihR : bihL;
    const float* bhh = dir ? bhhR : bhhL;
    const float* bfc = dir ? bfcR : bfcL;
    const float* wih1 = (dir ? wihR : wihL) + (size_t)2048 * 256;
    ba[dir * 2048 + n] = bih[n] + bhh[n];
    float s = bih[2048 + n] + bhh[2048 + n];
    #pragma unroll 8
    for (int v = 0; v < 256; ++v)
        s = fmaf(bfc[v], wih1[(size_t)n * 256 + v], s);
    bb[dir * 2048 + n] = s;
    if (n < 256) bc[dir * 256 + n] = bfc[256 + n];
}

// ---------------- main persistent kernel ----------------
// 256 blocks x 256 threads, co-resident (0 LDS, 1 block/CU fits).
// XCD-pinned decomposition (bid%8 -> XCD heuristic, perf-only): the 4 mq-sibling
// blocks sharing a weight slice get the same bid%8 -> same XCD -> weight slice
// stays in that XCD's L2 (per-XCD weight set ~3.75 MiB vs 4 MiB L2).
//   xcd=bid&7, slot=bid>>3, mq=slot>>3, p=slot&7, pairidx=xcd*8+p,
//   dir=pairidx&1, nslc=pairidx>>1.
// All h reads are coherent sc0/sc1 loads (no buffer_inv anywhere); h written as
// bf16 hi/lo pairs; c fp32 in VGPRs; GEMMs = 2-term bf16 split (3 MFMAs/product).
__global__ __launch_bounds__(256) void bilstm_main(
    const float* __restrict__ x,
    const bf16* __restrict__ wah, const bf16* __restrict__ wal,
    const bf16* __restrict__ wbh, const bf16* __restrict__ wbl,
    const bf16* __restrict__ wch, const bf16* __restrict__ wcl,
    bf16* __restrict__ h0pk, bf16* __restrict__ h1pk,
    const float* __restrict__ ba, const float* __restrict__ bb,
    const float* __restrict__ bc, float* __restrict__ out,
    unsigned* __restrict__ flags)
{
    const int bid  = blockIdx.x;
    const int xcd  = bid & 7;
    const int slot = bid >> 3;
    const int mq   = slot >> 3;
    const int p8   = slot & 7;
    const int pairidx = xcd * 8 + p8;
    const int dir  = pairidx & 1;
    const int nslc = pairidx >> 1;
    const int wv   = threadIdx.x >> 6;
    const int lane = threadIdx.x & 63;
    const int r = lane & 15, q = lane >> 4;
    const int tm = mq * 4 + wv;

    const bf16* WAh = wah + (size_t)dir * WA_UNITS_DIR * UNITE;
    const bf16* WAl = wal + (size_t)dir * WA_UNITS_DIR * UNITE;
    const bf16* WBh = wbh + (size_t)dir * WB_UNITS_DIR * UNITE;
    const bf16* WBl = wbl + (size_t)dir * WB_UNITS_DIR * UNITE;
    const bf16* WCh = wch + (size_t)dir * WC_UNITS_DIR * UNITE;
    const bf16* WCl = wcl + (size_t)dir * WC_UNITS_DIR * UNITE;
    bf16* H0 = h0pk + (size_t)dir * 4 * HPAR;   // [parity][part][HPAR]
    bf16* H1 = h1pk + (size_t)dir * 4 * HPAR;
    const float* BA = ba + dir * 2048;
    const float* BB = bb + dir * 2048;
    const float* BC = bc + dir * 256;

    const int col = nslc * 16 + r;               // hidden col this lane owns
    const int blkK = col >> 5;
    const int kl = col & 31;
    const size_t hw_base = (size_t)(tm * 16 + blkK) * UNITE
                         + (size_t)(kl >> 3) * 128 + (size_t)(4 * q) * 8 + (kl & 7);

    const float bia0 = BA[col], bia1 = BA[512 + col], bia2 = BA[1024 + col], bia3 = BA[1536 + col];
    const float bib0 = BB[col], bib1 = BB[512 + col], bib2 = BB[1024 + col], bib3 = BB[1536 + col];

    // y-tile assignment: per dir 512 wave-slots = 16 tm x 16 tn x 2 k-halves
    const int yid = (nslc * 4 + mq) * 4 + wv;
    const int ytm = yid & 15, ytn = (yid >> 4) & 15, ykh = yid >> 8;
    const float byc = (ykh == 0) ? BC[ytn * 16 + r] : 0.f;

    f32x4 c0 = {0.f, 0.f, 0.f, 0.f}, c1 = {0.f, 0.f, 0.f, 0.f};
    unsigned epoch = 0;

    for (int t = 0; t <= TSTEPS; ++t) {
        const int pw = t & 1, pr = pw ^ 1;
        // -------- phase A: gates0 + elementwise (t<255) --------
        if (t < TSTEPS) {
            const int pos = dir ? (255 - t) : t;
            f32x4 acc[4] = {{0,0,0,0},{0,0,0,0},{0,0,0,0},{0,0,0,0}};
            const float* xp = x + ((size_t)(tm * 16 + r) * 256 + pos) * 256 + q * 8;
            const bf16* ahh_p = H0 + (size_t)pr * 2 * HPAR + (size_t)(tm * 16) * UNITE + lane * 8;
            const bf16* ahl_p = ahh_p + HPAR;
            #pragma unroll
            for (int kb = 0; kb < 8; ++kb) {        // x part (K 0..255), cached loads, split in reg
                float xf[8];
                *(float4*)xf       = *(const float4*)(xp + kb * 32);
                *(float4*)(xf + 4) = *(const float4*)(xp + kb * 32 + 4);
                bf16x8 axh, axl;
                #pragma unroll
                for (int j = 0; j < 8; ++j) { bf16 h = (bf16)xf[j]; axh[j] = h; axl[j] = (bf16)(xf[j] - (float)h); }
                #pragma unroll
                for (int g = 0; g < 4; ++g) {
                    const size_t wu = ((size_t)((g * 32 + nslc) * 24) + kb) * UNITE + lane * 8;
                    bf16x8 bh = *(const bf16x8*)(WAh + wu);
                    bf16x8 bl = *(const bf16x8*)(WAl + wu);
                    MFMA(acc[g], axh, bh); MFMA(acc[g], axh, bl); MFMA(acc[g], axl, bh);
                }
            }
            #pragma unroll
            for (int kb0 = 0; kb0 < 16; kb0 += 4) { // h0 part (K 256..767), coherent loads
                u32x4 th[4], tl[4];
                load8_coh(ahh_p + (size_t)kb0 * UNITE, ahl_p + (size_t)kb0 * UNITE, th, tl);
                #pragma unroll
                for (int j = 0; j < 4; ++j) {
                    bf16x8 hh = __builtin_bit_cast(bf16x8, th[j]);
                    bf16x8 hl = __builtin_bit_cast(bf16x8, tl[j]);
                    const int kb = kb0 + j;
                    #pragma unroll
                    for (int g = 0; g < 4; ++g) {
                        const size_t wu = ((size_t)((g * 32 + nslc) * 24) + 8 + kb) * UNITE + lane * 8;
                        bf16x8 bh = *(const bf16x8*)(WAh + wu);
                        bf16x8 bl = *(const bf16x8*)(WAl + wu);
                        MFMA(acc[g], hh, bh); MFMA(acc[g], hh, bl); MFMA(acc[g], hl, bh);
                    }
                }
            }
            bf16* HwH = H0 + (size_t)pw * 2 * HPAR;
            bf16* HwL = HwH + HPAR;
            #pragma unroll
            for (int i = 0; i < 4; ++i) {
                float gi = sigmoidf_(acc[0][i] + bia0);
                float gf = sigmoidf_(acc[1][i] + bia1);
                float gg = tanhf_   (acc[2][i] + bia2);
                float go = sigmoidf_(acc[3][i] + bia3);
                float cc = gf * c0[i] + gi * gg;
                c0[i] = cc;
                float hv = go * tanhf_(cc);
                bf16 hh = (bf16)hv;
                HwH[hw_base + (size_t)i * 8] = hh;
                HwL[hw_base + (size_t)i * 8] = (bf16)(hv - (float)hh);
            }
        }
        // -------- phase A: y(t-1) = h1(t-1) @ wfc1^T + bfc1 (t>=1) --------
        if (t >= 1) {
            const int py = (t - 1) & 1;
            f32x4 acc = {0, 0, 0, 0};
            const bf16* ayh = H1 + (size_t)py * 2 * HPAR
                            + (size_t)(ytm * 16 + ykh * 8) * UNITE + lane * 8;
            const bf16* ayl = ayh + HPAR;
            #pragma unroll
            for (int kk0 = 0; kk0 < 8; kk0 += 4) {
                u32x4 th[4], tl[4];
                load8_coh(ayh + (size_t)kk0 * UNITE, ayl + (size_t)kk0 * UNITE, th, tl);
                #pragma unroll
                for (int j = 0; j < 4; ++j) {
                    const int kb = ykh * 8 + kk0 + j;
                    const size_t wu = (size_t)(ytn * 16 + kb) * UNITE + lane * 8;
                    bf16x8 bh = *(const bf16x8*)(WCh + wu);
                    bf16x8 bl = *(const bf16x8*)(WCl + wu);
                    bf16x8 ah = __builtin_bit_cast(bf16x8, th[j]);
                    bf16x8 al = __builtin_bit_cast(bf16x8, tl[j]);
                    MFMA(acc, ah, bh); MFMA(acc, ah, bl); MFMA(acc, al, bh);
                }
            }
            const int tout = dir ? (255 + (t - 1)) : (t - 1);
            #pragma unroll
            for (int i = 0; i < 4; ++i) {
                size_t oidx = ((size_t)(ytm * 16 + 4 * q + i) * 510 + tout) * 256 + (ytn * 16 + r);
                atomicAdd(out + oidx, acc[i] + byc);
            }
        }
        ++epoch; gbarrier(flags, bid, epoch);
        // -------- phase B: gates1 + elementwise (t<255) --------
        if (t < TSTEPS) {
            f32x4 acc[4] = {{0,0,0,0},{0,0,0,0},{0,0,0,0},{0,0,0,0}};
            const bf16* a0h = H0 + (size_t)pw * 2 * HPAR + (size_t)(tm * 16) * UNITE + lane * 8;
            const bf16* a0l = a0h + HPAR;
            const bf16* a1h = H1 + (size_t)pr * 2 * HPAR + (size_t)(tm * 16) * UNITE + lane * 8;
            const bf16* a1l = a1h + HPAR;
            #pragma unroll
            for (int kb0 = 0; kb0 < 16; kb0 += 4) { // h0(t) part (K 0..511)
                u32x4 th[4], tl[4];
                load8_coh(a0h + (size_t)kb0 * UNITE, a0l + (size_t)kb0 * UNITE, th, tl);
                #pragma unroll
                for (int j = 0; j < 4; ++j) {
                    bf16x8 hh = __builtin_bit_cast(bf16x8, th[j]);
                    bf16x8 hl = __builtin_bit_cast(bf16x8, tl[j]);
                    const int kb = kb0 + j;
                    #pragma unroll
                    for (int g = 0; g < 4; ++g) {
                        const size_t wu = ((size_t)((g * 32 + nslc) * 32) + kb) * UNITE + lane * 8;
                        bf16x8 bh = *(const bf16x8*)(WBh + wu);
                        bf16x8 bl = *(const bf16x8*)(WBl + wu);
                        MFMA(acc[g], hh, bh); MFMA(acc[g], hh, bl); MFMA(acc[g], hl, bh);
                    }
                }
            }
            #pragma unroll
            for (int kb0 = 0; kb0 < 16; kb0 += 4) { // h1(t-1) part (K 512..1023)
                u32x4 th[4], tl[4];
                load8_coh(a1h + (size_t)kb0 * UNITE, a1l + (size_t)kb0 * UNITE, th, tl);
                #pragma unroll
                for (int j = 0; j < 4; ++j) {
                    bf16x8 hh = __builtin_bit_cast(bf16x8, th[j]);
                    bf16x8 hl = __builtin_bit_cast(bf16x8, tl[j]);
                    const int kb = kb0 + j;
                    #pragma unroll
                    for (int g = 0; g < 4; ++g) {
                        const size_t wu = ((size_t)((g * 32 + nslc) * 32) + 16 + kb) * UNITE + lane * 8;
                        bf16x8 bh = *(const bf16x8*)(WBh + wu);
                        bf16x8 bl = *(const bf16x8*)(WBl + wu);
                        MFMA(acc[g], hh, bh); MFMA(acc[g], hh, bl); MFMA(acc[g], hl, bh);
                    }
                }
            }
            bf16* HwH = H1 + (size_t)pw * 2 * HPAR;
            bf16* HwL = HwH + HPAR;
            #pragma unroll
            for (int i = 0; i < 4; ++i) {
                float gi = sigmoidf_(acc[0][i] + bib0);
                float gf = sigmoidf_(acc[1][i] + bib1);
                float gg = tanhf_   (acc[2][i] + bib2);
                float go = sigmoidf_(acc[3][i] + bib3);
                float cc = gf * c1[i] + gi * gg;
                c1[i] = cc;
                float hv = go * tanhf_(cc);
                bf16 hh = (bf16)hv;
                HwH[hw_base + (size_t)i * 8] = hh;
                HwL[hw_base + (size_t)i * 8] = (bf16)(hv - (float)hh);
            }
        }
        ++epoch; gbarrier(flags, bid, epoch);
    }
}

// ---------------- host launch ----------------
extern "C" void kernel_launch(void* const* d_in, const int* in_sizes, int n_in,
                              void* d_out, int out_size, void* d_ws, size_t ws_size,
                              hipStream_t stream) {
    (void)in_sizes; (void)n_in; (void)ws_size;
    const float* x    = (const float*)d_in[0];
    const float* wihL = (const float*)d_in[1];
    const float* whhL = (const float*)d_in[2];
    const float* bihL = (const float*)d_in[3];
    const float* bhhL = (const float*)d_in[4];
    const float* wfcL = (const float*)d_in[5];
    const float* bfcL = (const float*)d_in[6];
    const float* wihR = (const float*)d_in[7];
    const float* whhR = (const float*)d_in[8];
    const float* bihR = (const float*)d_in[9];
    const float* bhhR = (const float*)d_in[10];
    const float* wfcR = (const float*)d_in[11];
    const float* bfcR = (const float*)d_in[12];

    char* ws = (char*)d_ws;
    size_t off = 0;
    auto take = [&](size_t bytes) -> char* {
        off = (off + 255) & ~(size_t)255;
        char* p = ws + off;
        off += bytes;
        return p;
    };
    bf16*     WAH = (bf16*)take((size_t)2 * WA_UNITS_DIR * 1024);  // 6 MiB
    bf16*     WAL = (bf16*)take((size_t)2 * WA_UNITS_DIR * 1024);  // 6 MiB
    bf16*     WBH = (bf16*)take((size_t)2 * WB_UNITS_DIR * 1024);  // 8 MiB
    bf16*     WBL = (bf16*)take((size_t)2 * WB_UNITS_DIR * 1024);  // 8 MiB
    bf16*     WCH = (bf16*)take((size_t)2 * WC_UNITS_DIR * 1024);  // 0.5 MiB
    bf16*     WCL = (bf16*)take((size_t)2 * WC_UNITS_DIR * 1024);  // 0.5 MiB
    bf16*     H0  = (bf16*)take((size_t)8 * HPAR * 2);             // 2 MiB (dir x parity x part)
    bf16*     H1  = (bf16*)take((size_t)8 * HPAR * 2);             // 2 MiB
    float*    WCF = (float*)take((size_t)2 * 2048 * 512 * 4);      // 8 MiB fp32 scratch
    float*    BA  = (float*)take((size_t)2 * 2048 * 4);
    float*    BB  = (float*)take((size_t)2 * 2048 * 4);
    float*    BC  = (float*)take((size_t)2 * 256 * 4);
    unsigned* FLG = (unsigned*)take((size_t)256 * 4);              // barrier flags

    hipMemsetAsync(H0, 0, (size_t)8 * HPAR * 2, stream);
    hipMemsetAsync(H1, 0, (size_t)8 * HPAR * 2, stream);
    hipMemsetAsync(FLG, 0, (size_t)256 * 4, stream);               // clear 0xAA poison!
    hipMemsetAsync(d_out, 0, (size_t)out_size * 4, stream);

    k_pack_wa<<<1536, 256, 0, stream>>>(wihL, whhL, wihR, whhR, WAH, WAL);
    k_wcomb  <<<8192, 256, 0, stream>>>(wihL, wfcL, wihR, wfcR, WCF);
    k_pack_wb<<<2048, 256, 0, stream>>>(whhL, whhR, WCF, WBH, WBL);
    k_pack_wc<<<128,  256, 0, stream>>>(wfcL, wfcR, WCH, WCL);
    k_bias   <<<16,   256, 0, stream>>>(bihL, bhhL, bfcL, wihL, bihR, bhhR, bfcR, wihR, BA, BB, BC);

    bilstm_main<<<256, 256, 0, stream>>>(x, WAH, WAL, WBH, WBL, WCH, WCL,
                                         H0, H1, BA, BB, BC, (float*)d_out, FLG);
}